// Round 15
// baseline (160.664 us; speedup 1.0000x reference)
//
#include <hip/hip_runtime.h>
#include <hip/hip_bf16.h>

#define N_NODES 100000
#define N_EDGES 3200000
#define IN_F 256
#define OUT_F 128

typedef __attribute__((ext_vector_type(8))) short bf16x8;
typedef __attribute__((ext_vector_type(4))) float f32x4;

__device__ __forceinline__ unsigned short f2bf(float f) {
    unsigned int u = __float_as_uint(f);
    u += 0x7fffu + ((u >> 16) & 1u);   // round-to-nearest-even
    return (unsigned short)(u >> 16);
}

__device__ __forceinline__ short cvt_bf16(float f) {
    __hip_bfloat16 b = (__hip_bfloat16)f;      // native cvt (pairs -> v_cvt_pk_bf16_f32)
    return *reinterpret_cast<short*>(&b);
}

// ---- Kernel 0: fused init: Wt transpose+convert AND CSR row_ptr ----
__global__ void k_init(const float* __restrict__ W, unsigned short* __restrict__ Wt,
                       const int* __restrict__ erow, int* __restrict__ row_ptr) {
    int e = blockIdx.x * 256 + threadIdx.x;
    if (e < IN_F * OUT_F) {            // W [256][128] f32 -> Wt [128][256] bf16
        int k = e >> 7;
        int c = e & 127;
        Wt[c * IN_F + k] = f2bf(W[e]);
    }
    if (e >= N_EDGES) return;
    int r = erow[e];
    int rprev = (e == 0) ? -1 : erow[e - 1];
    for (int rr = rprev + 1; rr <= r; ++rr) row_ptr[rr] = e;
    if (e == N_EDGES - 1) {
        for (int rr = r + 1; rr <= N_NODES; ++rr) row_ptr[rr] = N_EDGES;
    }
}

// ---- Kernel 2: H8 = int8 quant of tanh(A @ W). 64-row tiles (1563 blocks,
//      ~6 blocks/CU: 2x waves/SIMD vs 128-row tiles, smaller dispatch tail).
//      Each wave: 16 DISTINCT rows x all 128 cols (acc[8]). Depth-2
//      A-prefetch with parity-indexed stage registers (static indexing).
//      B loaded per-MFMA-pair to limit live VGPRs. Fast tanh via __expf. ----
__global__ __launch_bounds__(256, 4) void k_gemm(const float* __restrict__ A,
                                                 const unsigned short* __restrict__ Wt,
                                                 signed char* __restrict__ H8,
                                                 const int* __restrict__ activep) {
    const int tid  = threadIdx.x;
    const int lane = tid & 63;
    const int wid  = tid >> 6;   // 0..3: 16-row slice of the 64-row tile
    const int brow = blockIdx.x * 64;
    const int l15  = lane & 15;
    const int lk   = (lane >> 4) * 8;  // k-offset of this lane's 8 elems

    int row0 = brow + wid * 16 + l15;
    if (row0 > N_NODES - 1) row0 = N_NODES - 1;     // clamp OOB reads
    const float* ap = A + (long)row0 * IN_F + lk;
    const unsigned short* bp = Wt + (long)l15 * IN_F + lk;

    f32x4 acc[8] = {};

    // two pipeline stages of raw A data (depth-2, parity-indexed)
    float4 s0[2], s1[2];
    s0[0] = *(const float4*)(ap);          // k = 0
    s1[0] = *(const float4*)(ap + 4);
    s0[1] = *(const float4*)(ap + 32);     // k = 32
    s1[1] = *(const float4*)(ap + 36);

    #pragma unroll
    for (int step = 0; step < 8; ++step) {
        const int k0  = step * 32;
        const int par = step & 1;

        // consume current stage into the bf16 A-frag
        const float4 f0 = s0[par];
        const float4 f1 = s1[par];
        bf16x8 a;
        a[0] = cvt_bf16(f0.x); a[1] = cvt_bf16(f0.y);
        a[2] = cvt_bf16(f0.z); a[3] = cvt_bf16(f0.w);
        a[4] = cvt_bf16(f1.x); a[5] = cvt_bf16(f1.y);
        a[6] = cvt_bf16(f1.z); a[7] = cvt_bf16(f1.w);

        // refill this stage with the k-step 2 ahead (issue early, wait late)
        const int kl = k0 + 64;
        if (kl < IN_F) {
            s0[par] = *(const float4*)(ap + kl);
            s1[par] = *(const float4*)(ap + kl + 4);
        }

        // B frags in pairs (L1/L2-resident Wt), MFMA per pair
        #pragma unroll
        for (int n = 0; n < 8; n += 2) {
            bf16x8 b0 = *(const bf16x8*)(bp + (long)(n    ) * 16 * IN_F + k0);
            bf16x8 b1 = *(const bf16x8*)(bp + (long)(n + 1) * 16 * IN_F + k0);
            acc[n]     = __builtin_amdgcn_mfma_f32_16x16x32_bf16(a, b0, acc[n],     0, 0, 0);
            acc[n + 1] = __builtin_amdgcn_mfma_f32_16x16x32_bf16(a, b1, acc[n + 1], 0, 0, 0);
        }
    }

    const int act = *activep;
    const float qs = act ? 127.0f : 16.0f;
    // C/D layout: col = lane&15, row = (lane>>4)*4 + reg   [m89-verified]
    #pragma unroll
    for (int n = 0; n < 8; ++n) {
        #pragma unroll
        for (int r = 0; r < 4; ++r) {
            int row = brow + wid * 16 + (lane >> 4) * 4 + r;
            int col = n * 16 + l15;
            if (row < N_NODES) {
                float v = acc[n][r];
                if (act) {
                    float t = __expf(2.0f * v);          // tanh via exp
                    v = 1.0f - __fdividef(2.0f, t + 1.0f);
                }
                float q = v * qs;
                q = fminf(fmaxf(q, -127.0f), 127.0f);
                H8[(long)row * OUT_F + col] = (signed char)__float2int_rn(q);
            }
        }
    }
}

// ---- Kernel 3: SpMM over int8 h (128B rows) — R8-EXACT (best measured:
//      100.3us, VGPR 28, FETCH 167MB, VALUBusy 45%). One wave per row.
//      16 lanes x 8B (uint2) cover one edge's 128B row; one gather
//      instruction covers 4 edges. 16 edges/iter. Invalid lanes clamp
//      the edge index to e-1 so dead gathers coalesce with live ones.
//      Unpack: sign-extract + cvt + fma; scale folded into edge val.
//      shfl_xor(16/32) butterfly at row end. ----
__global__ __launch_bounds__(256) void k_spmm(const int* __restrict__ row_ptr,
                                              const int* __restrict__ ecol,
                                              const float* __restrict__ eval,
                                              const signed char* __restrict__ h8,
                                              const int* __restrict__ activep,
                                              float* __restrict__ out) {
    const int lane = threadIdx.x & 63;
    const int w    = threadIdx.x >> 6;
    const int r    = blockIdx.x * 4 + w;
    if (r >= N_NODES) return;

    const int q   = lane >> 4;        // edge slot 0..3 within wave
    const int l15 = lane & 15;

    const int s = __builtin_amdgcn_readfirstlane(row_ptr[r]);
    const int e = __builtin_amdgcn_readfirstlane(row_ptr[r + 1]);
    const int act = __builtin_amdgcn_readfirstlane(*activep);
    const float invs = act ? (1.0f / 127.0f) : (1.0f / 16.0f);

    // lane's 8 bytes within a 128B h row
    const signed char* hq = h8 + l15 * 8;

    float f0 = 0.f, f1 = 0.f, f2 = 0.f, f3 = 0.f;
    float f4 = 0.f, f5 = 0.f, f6 = 0.f, f7 = 0.f;

    for (int j = s; j < e; j += 16) {
        int   cc[4];
        float vv[4];
        #pragma unroll
        for (int u = 0; u < 4; ++u) {
            const int want = j + u * 4 + q;
            const int idx  = min(want, e - 1);     // always in-bounds (e>s here)
            cc[u] = ecol[idx];
            vv[u] = (want < e) ? eval[idx] * invs : 0.f;  // predicate + scale
        }
        uint2 g[4];
        #pragma unroll
        for (int u = 0; u < 4; ++u)
            g[u] = *(const uint2*)(hq + (((unsigned)cc[u]) << 7));
        #pragma unroll
        for (int u = 0; u < 4; ++u) {
            const float v = vv[u];
            const unsigned x = g[u].x, y = g[u].y;
            f0 = fmaf(v, (float)((signed char)(x      )), f0);
            f1 = fmaf(v, (float)((signed char)(x >>  8)), f1);
            f2 = fmaf(v, (float)((signed char)(x >> 16)), f2);
            f3 = fmaf(v, (float)((int)x >> 24),           f3);
            f4 = fmaf(v, (float)((signed char)(y      )), f4);
            f5 = fmaf(v, (float)((signed char)(y >>  8)), f5);
            f6 = fmaf(v, (float)((signed char)(y >> 16)), f6);
            f7 = fmaf(v, (float)((int)y >> 24),           f7);
        }
    }

    // reduce the 4 edge slots: lanes l, l+16, l+32, l+48 hold the same columns
    #pragma unroll
    for (int mask = 16; mask <= 32; mask <<= 1) {
        f0 += __shfl_xor(f0, mask);
        f1 += __shfl_xor(f1, mask);
        f2 += __shfl_xor(f2, mask);
        f3 += __shfl_xor(f3, mask);
        f4 += __shfl_xor(f4, mask);
        f5 += __shfl_xor(f5, mask);
        f6 += __shfl_xor(f6, mask);
        f7 += __shfl_xor(f7, mask);
    }

    if (q == 0) {
        float* dst = out + (long)r * OUT_F + l15 * 8;
        float4 o0; o0.x = f0; o0.y = f1; o0.z = f2; o0.w = f3;
        float4 o1; o1.x = f4; o1.y = f5; o1.z = f6; o1.w = f7;
        *(float4*)dst       = o0;
        *(float4*)(dst + 4) = o1;
    }
}

extern "C" void kernel_launch(void* const* d_in, const int* in_sizes, int n_in,
                              void* d_out, int out_size, void* d_ws, size_t ws_size,
                              hipStream_t stream) {
    const float* features = (const float*)d_in[0];
    const float* weight   = (const float*)d_in[1];
    const int*   erow     = (const int*)d_in[2];
    const int*   ecol     = (const int*)d_in[3];
    const float* evalp    = (const float*)d_in[4];
    const int*   activep  = (const int*)d_in[5];
    float* out = (float*)d_out;

    char* ws = (char*)d_ws;
    signed char* H8    = (signed char*)ws;                            // 12,800,000 B
    unsigned short* Wt = (unsigned short*)(ws + 12800000);            //     65,536 B
    int* row_ptr       = (int*)(ws + 12800000 + 65536);               //    400,004 B

    k_init <<<(N_EDGES + 255) / 256, 256, 0, stream>>>(weight, Wt, erow, row_ptr);
    k_gemm <<<(N_NODES + 63) / 64, 256, 0, stream>>>(features, Wt, H8, activep);
    k_spmm <<<(N_NODES + 3) / 4, 256, 0, stream>>>(row_ptr, ecol, evalp,
                                                   H8, activep, out);
}